// Round 1
// baseline (93.739 us; speedup 1.0000x reference)
//
#include <hip/hip_runtime.h>

// LayerStacks fused kernel.
// Per-bucket LDS layout (floats), bucket stride BSTR chosen so that
// BSTR % 32 == 4  =>  the 6 buckets' identical-offset b128 reads hit
// 6 disjoint 4-bank groups (conflict-free multi-broadcast).
#define NB 6
#define BSTR 4580
#define O_W1B  0      // 8 rows x 132 (cols 0..128 valid)
#define O_W1PA 1056   // 8 rows x 132
#define O_W2   2112   // 64 rows x 32
#define O_WOUT 4160   // 320
#define O_B1B  4480   // 8
#define O_B1PA 4488   // 8
#define O_B2   4496   // 64
#define O_BOUT 4560   // 1

__global__ __launch_bounds__(1024, 1)
void layerstacks_kernel(const float* __restrict__ x_base,
                        const float* __restrict__ x_pa,
                        const float* __restrict__ mobility,
                        const int*   __restrict__ ply,
                        const float* __restrict__ W1b,
                        const float* __restrict__ b1b,
                        const float* __restrict__ W1pa,
                        const float* __restrict__ b1pa,
                        const float* __restrict__ W2,
                        const float* __restrict__ b2,
                        const float* __restrict__ Wout,
                        const float* __restrict__ bout,
                        float* __restrict__ out)
{
    __shared__ float lds[NB * BSTR];   // ~107.3 KB (gfx950 allows up to 160 KB)
    const int tid = threadIdx.x;

    // ---------------- stage all weights into LDS (coalesced global reads) ----
    for (int e = tid; e < NB * 8 * 129; e += 1024) {
        int b = e / 1032; int r = e - b * 1032;
        int row = r / 129; int col = r - row * 129;
        lds[b * BSTR + O_W1B + row * 132 + col] = W1b[e];
    }
    for (int e = tid; e < NB * 8 * 129; e += 1024) {
        int b = e / 1032; int r = e - b * 1032;
        int row = r / 129; int col = r - row * 129;
        lds[b * BSTR + O_W1PA + row * 132 + col] = W1pa[e];
    }
    for (int e = tid; e < NB * 2048; e += 1024) {
        int b = e >> 11; int r = e & 2047;
        lds[b * BSTR + O_W2 + r] = W2[e];
    }
    for (int e = tid; e < NB * 320; e += 1024) {
        int b = e / 320; int r = e - b * 320;
        lds[b * BSTR + O_WOUT + r] = Wout[e];
    }
    if (tid < NB * 8) {
        int b = tid >> 3, r = tid & 7;
        lds[b * BSTR + O_B1B + r]  = b1b[tid];
        lds[b * BSTR + O_B1PA + r] = b1pa[tid];
    }
    for (int e = tid; e < NB * 64; e += 1024) {
        int b = e >> 6, r = e & 63;
        lds[b * BSTR + O_B2 + r] = b2[e];
    }
    if (tid < NB) lds[tid * BSTR + O_BOUT] = bout[tid];
    __syncthreads();

    // ---------------- per-sample compute ------------------------------------
    const int s = blockIdx.x * 1024 + tid;          // grid sized exactly B/1024
    const int idx = ply[s] / 10;                    // bucket 0..5
    const float* bk = &lds[idx * BSTR];
    const float mob = fminf(mobility[s] * (7.0f / 255.0f), 1.0f);

    // L1 accumulators, pre-seeded with bias + mobility (col 128) contribution
    float acc1[16];
    #pragma unroll
    for (int j = 0; j < 8; ++j)
        acc1[j] = bk[O_B1B + j] + bk[O_W1B + j * 132 + 128] * mob;
    #pragma unroll
    for (int j = 0; j < 8; ++j)
        acc1[8 + j] = bk[O_B1PA + j] + bk[O_W1PA + j * 132 + 128] * mob;

    float accout = bk[O_BOUT];   // bout (zeros, but keep exact)

    const float4* xb4 = reinterpret_cast<const float4*>(x_base + (size_t)s * 128);
    const float4* xp4 = reinterpret_cast<const float4*>(x_pa   + (size_t)s * 128);

    // Stream x_base once: feeds both L1-base rows AND Wout[64:192] dot.
    #pragma unroll 4
    for (int c = 0; c < 32; ++c) {
        const float4 x = xb4[c];
        #pragma unroll
        for (int j = 0; j < 8; ++j) {
            const float4 w = *reinterpret_cast<const float4*>(&bk[O_W1B + j * 132 + c * 4]);
            acc1[j] += w.x * x.x + w.y * x.y + w.z * x.z + w.w * x.w;
        }
        const float4 wo = *reinterpret_cast<const float4*>(&bk[O_WOUT + 64 + c * 4]);
        accout += wo.x * x.x + wo.y * x.y + wo.z * x.z + wo.w * x.w;
    }
    // Stream x_pa once: feeds L1-pa rows AND Wout[192:320] dot.
    #pragma unroll 4
    for (int c = 0; c < 32; ++c) {
        const float4 x = xp4[c];
        #pragma unroll
        for (int j = 0; j < 8; ++j) {
            const float4 w = *reinterpret_cast<const float4*>(&bk[O_W1PA + j * 132 + c * 4]);
            acc1[8 + j] += w.x * x.x + w.y * x.y + w.z * x.z + w.w * x.w;
        }
        const float4 wo = *reinterpret_cast<const float4*>(&bk[O_WOUT + 192 + c * 4]);
        accout += wo.x * x.x + wo.y * x.y + wo.z * x.z + wo.w * x.w;
    }

    // l1c = clip([l1^2 * 255/256, l1], 0, 1)
    float l1c[32];
    #pragma unroll
    for (int k = 0; k < 16; ++k) {
        const float v = acc1[k];
        l1c[16 + k] = fminf(fmaxf(v, 0.0f), 1.0f);
        l1c[k] = fminf(v * v * (255.0f / 256.0f), 1.0f);   // square is >= 0
    }

    // L2 (64x32) fused with Wout[0:64] dot
    #pragma unroll 4
    for (int j = 0; j < 64; ++j) {
        float a = bk[O_B2 + j];
        #pragma unroll
        for (int k = 0; k < 32; k += 4) {
            const float4 w = *reinterpret_cast<const float4*>(&bk[O_W2 + j * 32 + k]);
            a += w.x * l1c[k] + w.y * l1c[k + 1] + w.z * l1c[k + 2] + w.w * l1c[k + 3];
        }
        a = fminf(fmaxf(a, 0.0f), 1.0f);
        a = a * a * (255.0f / 256.0f);
        accout += bk[O_WOUT + j] * a;
    }

    out[s] = accout;
}

extern "C" void kernel_launch(void* const* d_in, const int* in_sizes, int n_in,
                              void* d_out, int out_size, void* d_ws, size_t ws_size,
                              hipStream_t stream) {
    const float* x_base   = (const float*)d_in[0];
    const float* x_pa     = (const float*)d_in[1];
    const float* mobility = (const float*)d_in[2];
    const int*   ply      = (const int*)d_in[3];
    const float* W1b      = (const float*)d_in[4];
    const float* b1b      = (const float*)d_in[5];
    const float* W1pa     = (const float*)d_in[6];
    const float* b1pa     = (const float*)d_in[7];
    const float* W2       = (const float*)d_in[8];
    const float* b2       = (const float*)d_in[9];
    const float* Wout     = (const float*)d_in[10];
    const float* bout     = (const float*)d_in[11];
    float* out = (float*)d_out;

    const int B = in_sizes[3];            // 262144
    const int blocks = B / 1024;          // 256 blocks x 1024 threads, exact
    layerstacks_kernel<<<blocks, 1024, 0, stream>>>(
        x_base, x_pa, mobility, ply, W1b, b1b, W1pa, b1pa, W2, b2, Wout, bout, out);
}